// Round 7
// baseline (4800.868 us; speedup 1.0000x reference)
//
#include <hip/hip_runtime.h>
#include <math.h>

#define Bb   16
#define Tt   2048
#define Dd   1024
#define NL   4
#define MTOT (Bb * Tt)   // 32768

typedef float f32x4 __attribute__((ext_vector_type(4)));
typedef short bf16x8 __attribute__((ext_vector_type(8)));

// ---------------------------------------------------------------------------
__device__ __forceinline__ unsigned short f2bf_rne(float x) {
    unsigned u = __float_as_uint(x);
    u += 0x7fffu + ((u >> 16) & 1u);
    return (unsigned short)(u >> 16);
}
__device__ __forceinline__ float bf2f(unsigned short h) {
    return __uint_as_float(((unsigned)h) << 16);
}
__device__ __forceinline__ float gelu_tanh(float x) {
    float x3 = x * x * x;
    float u  = 0.7978845608028654f * (x + 0.044715f * x3);
    return 0.5f * x * (1.0f + tanhf(u));
}
// async 16B global -> LDS (HW: wave-uniform LDS base + lane*16)
__device__ __forceinline__ void dma16(const void* g, void* l) {
    __builtin_amdgcn_global_load_lds(
        (const __attribute__((address_space(1))) unsigned int*)g,
        (__attribute__((address_space(3))) unsigned int*)l, 16, 0, 0);
}

// ---------------------------------------------------------------------------
// Split a [1024,1024] fp32 matrix (row-major [k][n]) into bf16 hi/lo with
// k-tiled, slot-swizzled layout:
//   fragment (n, kt, sl) -> shorts offset ((kt*1024+n)*4 + (sl^((n>>1)&3)))*8
// so the GEMM can DMA each k-tile linearly into LDS and read conflict-free.
// (unchanged from round 6 — proven)
// ---------------------------------------------------------------------------
__global__ __launch_bounds__(256)
void split_bt(const float* __restrict__ B, short* __restrict__ ht,
              short* __restrict__ lt)
{
    __shared__ float tile[32][33];
    const int t  = threadIdx.x;
    const int r  = t >> 3;          // 0..31
    const int c  = (t & 7) * 4;     // 0,4,...,28
    const int kb = blockIdx.y * 32; // kt = blockIdx.y
    const int nb = blockIdx.x * 32;
    float4 v = *reinterpret_cast<const float4*>(
        &B[(size_t)(kb + r) * Dd + nb + c]);
    tile[r][c + 0] = v.x; tile[r][c + 1] = v.y;
    tile[r][c + 2] = v.z; tile[r][c + 3] = v.w;
    __syncthreads();
    unsigned h[4], lo[4];
#pragma unroll
    for (int q = 0; q < 4; ++q) {
        float f = tile[c + q][r];           // B[kb+c+q][nb+r]
        unsigned short hh = f2bf_rne(f);
        float rem = f - bf2f(hh);
        h[q]  = hh;
        lo[q] = f2bf_rne(rem);
    }
    uint2 hw, lw;
    hw.x = h[0]  | (h[1]  << 16); hw.y = h[2]  | (h[3]  << 16);
    lw.x = lo[0] | (lo[1] << 16); lw.y = lo[2] | (lo[3] << 16);
    const int n = nb + r;
    const int s = (c >> 3) ^ ((n >> 1) & 3);   // swizzled slot
    size_t off = ((size_t)(blockIdx.y * 1024 + n) * 4 + s) * 8 + (c & 4);
    *reinterpret_cast<uint2*>(&ht[off]) = hw;
    *reinterpret_cast<uint2*>(&lt[off]) = lw;
}

// ---------------------------------------------------------------------------
// Split-precision MFMA GEMM, 2-phase counted-vmcnt pipeline.
// 512 threads = 8 waves (2M x 4N); tile 128 x NT; each wave owns 64 x NT/4.
// Double-buffered A (reg-stage + convert) and B (global_load_lds DMA from the
// pre-swizzled split_bt layout). One raw s_barrier + vmcnt(0)/lgkmcnt(0) per
// k-tile; STAGE of tile t+1 issued before COMPUTE of tile t so HBM latency
// and convert VALU hide under MFMA.
// MODE 0: Cout = A@B (+bias)
// MODE 1: Cout[t] = Sin[t] + (t%Tt>=m ? A[t-m]@B : 0)
// MODE 2: rows [tstart,tstart+128) of each batch: Cout[r]=Sin[r]+A[r-128]@B
// BN 1:   also emit per-(m-tile, column) partial sum/sumsq (reuses LDS).
// ---------------------------------------------------------------------------
template<int MODE, int BN, int NT>
__global__ __launch_bounds__(512, 2)
void mfma_gemm(const float* __restrict__ A,
               const short* __restrict__ Bth, const short* __restrict__ Btl,
               const float* __restrict__ bias,
               const float* __restrict__ Sin,
               float* __restrict__ Cout,
               float* __restrict__ psum, float* __restrict__ psq,
               int m, int tstart)
{
    constexpr int NJ    = NT / 64;        // j-fragments per wave
    constexpr int BPL   = NT * 32;        // shorts per B plane per buffer
    constexpr int ABUF  = 10240;          // shorts per A buffer (hi+lo, 40-pad)
    constexpr int BBUF  = 2 * BPL;        // shorts per B buffer (hi+lo)
    constexpr int BBASE = 2 * ABUF;
    constexpr int NQ    = NT / 128;       // dma pairs per plane per thread
    __shared__ __align__(16) short lds[BBASE + 2 * BBUF];

    const int tid  = threadIdx.x;
    const int lane = tid & 63;
    const int w    = tid >> 6;            // 0..7
    const int n0   = blockIdx.x * NT;
    const int m0g  = (MODE == 2) ? (blockIdx.y * Tt + tstart)
                                 : (blockIdx.y * 128);
    const int wm0  = (w >> 2) * 64;
    const int wn0  = (w & 3) * (NT / 4);

    // ---- A staging map: thread covers row ar, k-span [ac, ac+8) ----
    const int ar = tid >> 2;              // 0..127
    const int ac = (tid & 3) * 8;
    const int rg = m0g + ar;
    bool avalid = true;
    if (MODE >= 1) { int t = rg & (Tt - 1); avalid = (t >= m); }
    const size_t arow = (size_t)((MODE >= 1 && avalid) ? (rg - m) : rg);
    const int awo = ar * 40 + ac;

    // ---- fragment read offsets (within a buffer) ----
    int a_off[4];
#pragma unroll
    for (int i = 0; i < 4; ++i)
        a_off[i] = (wm0 + i * 16 + (lane & 15)) * 40 + (lane >> 4) * 8;
    const int ln  = lane & 15;
    const int nlb = wn0 + ln;
    const int b_off0 = nlb * 32 + (((lane >> 4) ^ ((nlb >> 1) & 3)) << 3);

    // ---- B dma map ----
    int bnq[NQ], bsq[NQ], bcq[NQ];
#pragma unroll
    for (int q = 0; q < NQ; ++q) {
        int c = w + q * 8;
        int f = c * 64 + lane;
        bcq[q] = c; bnq[q] = f >> 2; bsq[q] = f & 3;
    }

    f32x4 acc[4][NJ];
#pragma unroll
    for (int i = 0; i < 4; ++i)
#pragma unroll
        for (int j = 0; j < NJ; ++j) acc[i][j] = (f32x4){0.f, 0.f, 0.f, 0.f};

    float4 aR0, aR1;

    auto LOADA = [&](int kt) {
        const float* p = &A[arow * Dd + kt * 32 + ac];
        aR0 = *reinterpret_cast<const float4*>(p);
        aR1 = *reinterpret_cast<const float4*>(p + 4);
    };
    auto CONVA = [&](int nb) {
        float f[8] = {aR0.x, aR0.y, aR0.z, aR0.w, aR1.x, aR1.y, aR1.z, aR1.w};
        if (MODE >= 1 && !avalid) {
#pragma unroll
            for (int e = 0; e < 8; ++e) f[e] = 0.f;
        }
        unsigned hh[8], ll[8];
#pragma unroll
        for (int e = 0; e < 8; ++e) {
            unsigned short h = f2bf_rne(f[e]);
            hh[e] = h;
            ll[e] = f2bf_rne(f[e] - bf2f(h));
        }
        int4 hw, lw;
        hw.x = (int)(hh[0] | (hh[1] << 16)); hw.y = (int)(hh[2] | (hh[3] << 16));
        hw.z = (int)(hh[4] | (hh[5] << 16)); hw.w = (int)(hh[6] | (hh[7] << 16));
        lw.x = (int)(ll[0] | (ll[1] << 16)); lw.y = (int)(ll[2] | (ll[3] << 16));
        lw.z = (int)(ll[4] | (ll[5] << 16)); lw.w = (int)(ll[6] | (ll[7] << 16));
        *reinterpret_cast<int4*>(&lds[nb * ABUF + awo])        = hw;
        *reinterpret_cast<int4*>(&lds[nb * ABUF + awo + 5120]) = lw;
    };
    auto STAGEB = [&](int kt, int nb) {
#pragma unroll
        for (int q = 0; q < NQ; ++q) {
            size_t g = ((size_t)(kt * 1024 + n0 + bnq[q]) * 4 + bsq[q]) * 8;
            short* d = &lds[BBASE + nb * BBUF + bcq[q] * 512];
            dma16(&Bth[g], d);
            dma16(&Btl[g], d + BPL);
        }
    };
    auto COMPUTE = [&](int nb) {
        const int ab = nb * ABUF;
        const int bb = BBASE + nb * BBUF;
        bf16x8 ah[4], al[4];
#pragma unroll
        for (int i = 0; i < 4; ++i) {
            ah[i] = *reinterpret_cast<const bf16x8*>(&lds[ab + a_off[i]]);
            al[i] = *reinterpret_cast<const bf16x8*>(&lds[ab + a_off[i] + 5120]);
        }
#pragma unroll
        for (int j = 0; j < NJ; ++j) {
            const bf16x8 bh = *reinterpret_cast<const bf16x8*>(
                &lds[bb + b_off0 + j * 512]);
            const bf16x8 bl = *reinterpret_cast<const bf16x8*>(
                &lds[bb + b_off0 + j * 512 + BPL]);
#pragma unroll
            for (int i = 0; i < 4; ++i) {
                acc[i][j] = __builtin_amdgcn_mfma_f32_16x16x32_bf16(
                    ah[i], bh, acc[i][j], 0, 0, 0);
                acc[i][j] = __builtin_amdgcn_mfma_f32_16x16x32_bf16(
                    ah[i], bl, acc[i][j], 0, 0, 0);
                acc[i][j] = __builtin_amdgcn_mfma_f32_16x16x32_bf16(
                    al[i], bh, acc[i][j], 0, 0, 0);
            }
        }
    };
    auto CLOSE = [&]() {
        asm volatile("s_waitcnt vmcnt(0) lgkmcnt(0)" ::: "memory");
        __builtin_amdgcn_s_barrier();
    };

    // ---- prologue: stage tile 0, prefetch tile 1's A ----
    LOADA(0);
    STAGEB(0, 0);
    CONVA(0);
    LOADA(1);
    CLOSE();

    // ---- main loop: one barrier per k-tile, stage-before-compute ----
    for (int kt = 0; kt < 32; ++kt) {
        const int cur = kt & 1;
        if (kt < 31) {
            STAGEB(kt + 1, cur ^ 1);
            CONVA(cur ^ 1);              // consumes aReg = tile kt+1
            if (kt < 30) LOADA(kt + 2);
        }
        COMPUTE(cur);
        CLOSE();
    }

    // ---- epilogue ----
    float* bnF = reinterpret_cast<float*>(lds);
    if (BN) {
        if (tid < 256) { bnF[tid] = 0.f; bnF[256 + tid] = 0.f; }
        __syncthreads();
    }
#pragma unroll
    for (int j = 0; j < NJ; ++j) {
        int cl  = wn0 + j * 16 + ln;
        int col = n0 + cl;
        float bj = (MODE == 0 && bias) ? bias[col] : 0.f;
        float sv = 0.f, sq = 0.f;
#pragma unroll
        for (int i = 0; i < 4; ++i) {
            int rbase = m0g + wm0 + i * 16 + (lane >> 4) * 4;
#pragma unroll
            for (int e = 0; e < 4; ++e) {
                size_t off = (size_t)(rbase + e) * Dd + col;
                float v = acc[i][j][e] + bj;
                if (MODE >= 1) v += Sin[off];
                Cout[off] = v;
                if (BN) { sv += v; sq += v * v; }
            }
        }
        if (BN) { atomicAdd(&bnF[cl], sv); atomicAdd(&bnF[256 + cl], sq); }
    }
    if (BN) {
        __syncthreads();
        if (tid < 256) {
            psum[(size_t)blockIdx.y * Dd + n0 + tid] = bnF[tid];
            psq [(size_t)blockIdx.y * Dd + n0 + tid] = bnF[256 + tid];
        }
    }
}

// ---------------------------------------------------------------------------
__global__ __launch_bounds__(256)
void bn_stats(const float* __restrict__ ps, const float* __restrict__ pq,
              const float* __restrict__ scale, const float* __restrict__ bias,
              float* __restrict__ Av, float* __restrict__ Cv)
{
    const int d = blockIdx.x * 256 + threadIdx.x;
    float s = 0.f, q = 0.f;
    for (int p = 0; p < 256; ++p) {
        s += ps[p * Dd + d];
        q += pq[p * Dd + d];
    }
    const float invN = 1.0f / 32768.0f;
    float mean = s * invN;
    float var  = q * invN - mean * mean;
    float rs   = rsqrtf(var + 1e-5f);
    float a    = rs * scale[d];
    Av[d] = a;
    Cv[d] = bias[d] - mean * a;
}

// ---------------------------------------------------------------------------
__global__ __launch_bounds__(256)
void residual_gelu(const float* __restrict__ Z, const float* __restrict__ Yin,
                   float* __restrict__ Yout,
                   const float* __restrict__ Av, const float* __restrict__ Cv)
{
    const float4* z4 = reinterpret_cast<const float4*>(Z);
    const float4* y4 = reinterpret_cast<const float4*>(Yin);
    float4*       o4 = reinterpret_cast<float4*>(Yout);
    const float4* a4 = reinterpret_cast<const float4*>(Av);
    const float4* c4 = reinterpret_cast<const float4*>(Cv);
    const int n4 = MTOT * Dd / 4;
    for (int i = blockIdx.x * blockDim.x + threadIdx.x; i < n4;
         i += gridDim.x * blockDim.x) {
        int d4 = i & (Dd / 4 - 1);
        float4 z = z4[i], y = y4[i], a = a4[d4], c = c4[d4];
        float4 o;
        o.x = gelu_tanh(fmaf(z.x, a.x, c.x)) + y.x;
        o.y = gelu_tanh(fmaf(z.y, a.y, c.y)) + y.y;
        o.z = gelu_tanh(fmaf(z.z, a.z, c.z)) + y.z;
        o.w = gelu_tanh(fmaf(z.w, a.w, c.w)) + y.w;
        o4[i] = o;
    }
}

// ---------------------------------------------------------------------------
extern "C" void kernel_launch(void* const* d_in, const int* in_sizes, int n_in,
                              void* d_out, int out_size, void* d_ws, size_t ws_size,
                              hipStream_t stream)
{
    const float* x    = (const float*)d_in[0];
    const float* Wi   = (const float*)d_in[1];
    const float* bi   = (const float*)d_in[2];
    const float* Wh   = (const float*)d_in[3];
    const float* mlpW = (const float*)d_in[4];
    const float* mlpb = (const float*)d_in[5];
    const float* bns  = (const float*)d_in[6];
    const float* bnb  = (const float*)d_in[7];
    float* out = (float*)d_out;

    float* ws   = (float*)d_ws;
    float* S0   = ws;                                  // 32M floats (128 MiB)
    float* Pa   = S0 + (size_t)MTOT * Dd;
    float* Pb   = Pa + (size_t)Dd * Dd;
    float* psum = Pb + (size_t)Dd * Dd;                // [256][1024]
    float* psq  = psum + 256 * Dd;
    float* abuf = psq + 256 * Dd;
    float* cbuf = abuf + Dd;
    short* Bth  = (short*)(cbuf + Dd);
    short* Btl  = Bth + (size_t)Dd * Dd;

    const dim3 gBig(4, 256);    // NT=256 tiles: 128x256, 512 threads
    const dim3 gSq (8, 8);      // NT=128 tiles: 128x128 (64 blocks)
    const dim3 gSeq(8, 16);     // NT=128 tiles (128 blocks)
    const dim3 gBt (32, 32);

#define SPLIT(M) split_bt<<<gBt, 256, 0, stream>>>((M), Bth, Btl)
#define GEMM(MODE, BN, NT, grid, A_, bias_, Sin_, C_, ps_, pq_, m_, ts_)      \
    mfma_gemm<MODE, BN, NT><<<grid, 512, 0, stream>>>(                        \
        (A_), Bth, Btl, (bias_), (Sin_), (C_), (ps_), (pq_), (m_), (ts_))

    // Phase 1: xp = x @ Wi + bi -> S0
    SPLIT(Wi);
    GEMM(0, 0, 256, gBig, x, bi, nullptr, S0, nullptr, nullptr, 0, 0);

    // Phase 2: 7 scan-doubling levels (window 128), powers interleaved.
    SPLIT(Wh);
    GEMM(1, 0, 256, gBig, S0, nullptr, S0, out, nullptr, nullptr, 1, 0);   // L1
    GEMM(0, 0, 128, gSq,  Wh, nullptr, nullptr, Pa, nullptr, nullptr, 0, 0); // P2
    SPLIT(Pa);
    GEMM(1, 0, 256, gBig, out, nullptr, out, S0, nullptr, nullptr, 2, 0);  // L2
    GEMM(0, 0, 128, gSq,  Pa, nullptr, nullptr, Pb, nullptr, nullptr, 0, 0); // P4
    SPLIT(Pb);
    GEMM(1, 0, 256, gBig, S0, nullptr, S0, out, nullptr, nullptr, 4, 0);   // L3
    GEMM(0, 0, 128, gSq,  Pb, nullptr, nullptr, Pa, nullptr, nullptr, 0, 0); // P8
    SPLIT(Pa);
    GEMM(1, 0, 256, gBig, out, nullptr, out, S0, nullptr, nullptr, 8, 0);  // L4
    GEMM(0, 0, 128, gSq,  Pa, nullptr, nullptr, Pb, nullptr, nullptr, 0, 0); // P16
    SPLIT(Pb);
    GEMM(1, 0, 256, gBig, S0, nullptr, S0, out, nullptr, nullptr, 16, 0);  // L5
    GEMM(0, 0, 128, gSq,  Pb, nullptr, nullptr, Pa, nullptr, nullptr, 0, 0); // P32
    SPLIT(Pa);
    GEMM(1, 0, 256, gBig, out, nullptr, out, S0, nullptr, nullptr, 32, 0); // L6
    GEMM(0, 0, 128, gSq,  Pa, nullptr, nullptr, Pb, nullptr, nullptr, 0, 0); // P64
    SPLIT(Pb);
    GEMM(1, 0, 256, gBig, S0, nullptr, S0, out, nullptr, nullptr, 64, 0);  // L7
    GEMM(0, 0, 128, gSq,  Pb, nullptr, nullptr, Pa, nullptr, nullptr, 0, 0); // P128
    SPLIT(Pa);

    // Phase 3: 15 sequential carry steps with P128 (in-place on out)
    for (int i = 1; i < 16; ++i)
        GEMM(2, 0, 128, gSeq, out, nullptr, out, out, nullptr, nullptr,
             128, 128 * i);

    // Phase 4: residual MLP stack; y stays in out, z in S0
    for (int l = 0; l < NL; ++l) {
        SPLIT(mlpW + (size_t)l * Dd * Dd);
        GEMM(0, 1, 256, gBig, out, mlpb + (size_t)l * Dd, nullptr, S0,
             psum, psq, 0, 0);
        bn_stats<<<4, 256, 0, stream>>>(psum, psq, bns + (size_t)l * Dd,
                                        bnb + (size_t)l * Dd, abuf, cbuf);
        residual_gelu<<<2048, 256, 0, stream>>>(S0, out, out, abuf, cbuf);
    }
#undef SPLIT
#undef GEMM
}

// Round 8
// 4712.322 us; speedup vs baseline: 1.0188x; 1.0188x over previous
//
#include <hip/hip_runtime.h>
#include <math.h>

#define Bb   16
#define Tt   2048
#define Dd   1024
#define NL   4
#define MTOT (Bb * Tt)   // 32768

typedef float f32x4 __attribute__((ext_vector_type(4)));
typedef short bf16x8 __attribute__((ext_vector_type(8)));

// ---------------------------------------------------------------------------
__device__ __forceinline__ unsigned short f2bf_rne(float x) {
    unsigned u = __float_as_uint(x);
    u += 0x7fffu + ((u >> 16) & 1u);
    return (unsigned short)(u >> 16);
}
__device__ __forceinline__ float bf2f(unsigned short h) {
    return __uint_as_float(((unsigned)h) << 16);
}
__device__ __forceinline__ float gelu_tanh(float x) {
    float x3 = x * x * x;
    float u  = 0.7978845608028654f * (x + 0.044715f * x3);
    return 0.5f * x * (1.0f + tanhf(u));
}
// async 16B global -> LDS (HW: wave-uniform LDS base + lane*16)
__device__ __forceinline__ void dma16(const void* g, void* l) {
    __builtin_amdgcn_global_load_lds(
        (const __attribute__((address_space(1))) unsigned int*)g,
        (__attribute__((address_space(3))) unsigned int*)l, 16, 0, 0);
}

// ---------------------------------------------------------------------------
// Split a [1024,1024] fp32 matrix (row-major [k][n]) into bf16 hi/lo with
// k-tiled, slot-swizzled layout:
//   fragment (n, kt, sl) -> shorts offset ((kt*1024+n)*4 + (sl^((n>>1)&3)))*8
// so the GEMM can DMA each k-tile linearly into LDS and read conflict-free.
// (unchanged — proven R6/R7)
// ---------------------------------------------------------------------------
__global__ __launch_bounds__(256)
void split_bt(const float* __restrict__ B, short* __restrict__ ht,
              short* __restrict__ lt)
{
    __shared__ float tile[32][33];
    const int t  = threadIdx.x;
    const int r  = t >> 3;          // 0..31
    const int c  = (t & 7) * 4;     // 0,4,...,28
    const int kb = blockIdx.y * 32; // kt = blockIdx.y
    const int nb = blockIdx.x * 32;
    float4 v = *reinterpret_cast<const float4*>(
        &B[(size_t)(kb + r) * Dd + nb + c]);
    tile[r][c + 0] = v.x; tile[r][c + 1] = v.y;
    tile[r][c + 2] = v.z; tile[r][c + 3] = v.w;
    __syncthreads();
    unsigned h[4], lo[4];
#pragma unroll
    for (int q = 0; q < 4; ++q) {
        float f = tile[c + q][r];           // B[kb+c+q][nb+r]
        unsigned short hh = f2bf_rne(f);
        float rem = f - bf2f(hh);
        h[q]  = hh;
        lo[q] = f2bf_rne(rem);
    }
    uint2 hw, lw;
    hw.x = h[0]  | (h[1]  << 16); hw.y = h[2]  | (h[3]  << 16);
    lw.x = lo[0] | (lo[1] << 16); lw.y = lo[2] | (lo[3] << 16);
    const int n = nb + r;
    const int s = (c >> 3) ^ ((n >> 1) & 3);   // swizzled slot
    size_t off = ((size_t)(blockIdx.y * 1024 + n) * 4 + s) * 8 + (c & 4);
    *reinterpret_cast<uint2*>(&ht[off]) = hw;
    *reinterpret_cast<uint2*>(&lt[off]) = lw;
}

// ---------------------------------------------------------------------------
// Split-precision MFMA GEMM, 2-phase pipeline with COUNTED vmcnt (T3+T4).
// 512 threads = 8 waves (2M x 4N); tile 128 x NT; each wave owns 64 x NT/4.
// Double-buffered A (reg-stage + convert + ds_write) and B (global_load_lds
// DMA from the pre-swizzled split_bt layout). Per k-tile: STAGE(t+1) issued
// BEFORE COMPUTE(t); close with s_waitcnt vmcnt(2) (B-DMA drained, A-prefetch
// stays in flight) + raw s_barrier. vmcnt(0) only at the last tile.
// MODE 0: Cout = A@B (+bias)
// MODE 1: Cout[t] = Sin[t] + (t%Tt>=m ? A[t-m]@B : 0)
// MODE 2: rows [tstart,tstart+128) of each batch: Cout[r]=Sin[r]+A[r-128]@B
// BN 1:   also emit per-(m-tile, column) partial sum/sumsq (reuses LDS).
// ---------------------------------------------------------------------------
template<int MODE, int BN, int NT>
__global__ __launch_bounds__(512, 2)
void mfma_gemm(const float* __restrict__ A,
               const short* __restrict__ Bth, const short* __restrict__ Btl,
               const float* __restrict__ bias,
               const float* __restrict__ Sin,
               float* __restrict__ Cout,
               float* __restrict__ psum, float* __restrict__ psq,
               int m, int tstart)
{
    constexpr int NJ    = NT / 64;        // j-fragments per wave
    constexpr int BPL   = NT * 32;        // shorts per B plane per buffer
    constexpr int ABUF  = 10240;          // shorts per A buffer (hi+lo, 40-pad)
    constexpr int BBUF  = 2 * BPL;        // shorts per B buffer (hi+lo)
    constexpr int BBASE = 2 * ABUF;
    constexpr int NQ    = NT / 128;       // dma pairs per plane per thread
    __shared__ __align__(16) short lds[BBASE + 2 * BBUF];

    const int tid  = threadIdx.x;
    const int lane = tid & 63;
    const int w    = tid >> 6;            // 0..7
    const int n0   = blockIdx.x * NT;
    const int m0g  = (MODE == 2) ? (blockIdx.y * Tt + tstart)
                                 : (blockIdx.y * 128);
    const int wm0  = (w >> 2) * 64;
    const int wn0  = (w & 3) * (NT / 4);

    // ---- A staging map: thread covers row ar, k-span [ac, ac+8) ----
    const int ar = tid >> 2;              // 0..127
    const int ac = (tid & 3) * 8;
    const int rg = m0g + ar;
    bool avalid = true;
    if (MODE >= 1) { int t = rg & (Tt - 1); avalid = (t >= m); }
    const size_t arow = (size_t)((MODE >= 1 && avalid) ? (rg - m) : rg);
    const int awo = ar * 40 + ac;

    // ---- fragment read offsets (within a buffer) ----
    int a_off[4];
#pragma unroll
    for (int i = 0; i < 4; ++i)
        a_off[i] = (wm0 + i * 16 + (lane & 15)) * 40 + (lane >> 4) * 8;
    const int ln  = lane & 15;
    const int nlb = wn0 + ln;
    const int b_off0 = nlb * 32 + (((lane >> 4) ^ ((nlb >> 1) & 3)) << 3);

    // ---- B dma map ----
    int bnq[NQ], bsq[NQ], bcq[NQ];
#pragma unroll
    for (int q = 0; q < NQ; ++q) {
        int c = w + q * 8;
        int f = c * 64 + lane;
        bcq[q] = c; bnq[q] = f >> 2; bsq[q] = f & 3;
    }

    f32x4 acc[4][NJ];
#pragma unroll
    for (int i = 0; i < 4; ++i)
#pragma unroll
        for (int j = 0; j < NJ; ++j) acc[i][j] = (f32x4){0.f, 0.f, 0.f, 0.f};

    float4 aR0, aR1;

    auto LOADA = [&](int kt) {
        const float* p = &A[arow * Dd + kt * 32 + ac];
        aR0 = *reinterpret_cast<const float4*>(p);
        aR1 = *reinterpret_cast<const float4*>(p + 4);
    };
    auto CONVA = [&](int nb) {
        float f[8] = {aR0.x, aR0.y, aR0.z, aR0.w, aR1.x, aR1.y, aR1.z, aR1.w};
        if (MODE >= 1 && !avalid) {
#pragma unroll
            for (int e = 0; e < 8; ++e) f[e] = 0.f;
        }
        unsigned hh[8], ll[8];
#pragma unroll
        for (int e = 0; e < 8; ++e) {
            unsigned short h = f2bf_rne(f[e]);
            hh[e] = h;
            ll[e] = f2bf_rne(f[e] - bf2f(h));
        }
        int4 hw, lw;
        hw.x = (int)(hh[0] | (hh[1] << 16)); hw.y = (int)(hh[2] | (hh[3] << 16));
        hw.z = (int)(hh[4] | (hh[5] << 16)); hw.w = (int)(hh[6] | (hh[7] << 16));
        lw.x = (int)(ll[0] | (ll[1] << 16)); lw.y = (int)(ll[2] | (ll[3] << 16));
        lw.z = (int)(ll[4] | (ll[5] << 16)); lw.w = (int)(ll[6] | (ll[7] << 16));
        *reinterpret_cast<int4*>(&lds[nb * ABUF + awo])        = hw;
        *reinterpret_cast<int4*>(&lds[nb * ABUF + awo + 5120]) = lw;
    };
    auto STAGEB = [&](int kt, int nb) {
#pragma unroll
        for (int q = 0; q < NQ; ++q) {
            size_t g = ((size_t)(kt * 1024 + n0 + bnq[q]) * 4 + bsq[q]) * 8;
            short* d = &lds[BBASE + nb * BBUF + bcq[q] * 512];
            dma16(&Bth[g], d);
            dma16(&Btl[g], d + BPL);
        }
    };
    auto COMPUTE = [&](int nb) {
        const int ab = nb * ABUF;
        const int bb = BBASE + nb * BBUF;
        bf16x8 ah[4], al[4];
#pragma unroll
        for (int i = 0; i < 4; ++i) {
            ah[i] = *reinterpret_cast<const bf16x8*>(&lds[ab + a_off[i]]);
            al[i] = *reinterpret_cast<const bf16x8*>(&lds[ab + a_off[i] + 5120]);
        }
        __builtin_amdgcn_s_setprio(1);
#pragma unroll
        for (int j = 0; j < NJ; ++j) {
            const bf16x8 bh = *reinterpret_cast<const bf16x8*>(
                &lds[bb + b_off0 + j * 512]);
            const bf16x8 bl = *reinterpret_cast<const bf16x8*>(
                &lds[bb + b_off0 + j * 512 + BPL]);
#pragma unroll
            for (int i = 0; i < 4; ++i) {
                acc[i][j] = __builtin_amdgcn_mfma_f32_16x16x32_bf16(
                    ah[i], bh, acc[i][j], 0, 0, 0);
                acc[i][j] = __builtin_amdgcn_mfma_f32_16x16x32_bf16(
                    ah[i], bl, acc[i][j], 0, 0, 0);
                acc[i][j] = __builtin_amdgcn_mfma_f32_16x16x32_bf16(
                    al[i], bh, acc[i][j], 0, 0, 0);
            }
        }
        __builtin_amdgcn_s_setprio(0);
    };

    // ---- prologue: tile 0 staged, tile 1's A in flight ----
    LOADA(0);
    CONVA(0);                         // compiler waits vmcnt for aR here
    STAGEB(0, 0);                     // 2*NQ dma issued (oldest in queue)
    __builtin_amdgcn_sched_barrier(0);
    LOADA(1);                         // 2 reg loads (newest)
    asm volatile("s_waitcnt vmcnt(2) lgkmcnt(0)" ::: "memory");
    __builtin_amdgcn_sched_barrier(0);
    __builtin_amdgcn_s_barrier();

    // ---- main loop: stage-before-compute, counted vmcnt close ----
    for (int kt = 0; kt < 32; ++kt) {
        const int cur = kt & 1;
        if (kt < 31) {
            STAGEB(kt + 1, cur ^ 1);      // dma (oldest outstanding)
            CONVA(cur ^ 1);               // consumes aReg = tile kt+1
            __builtin_amdgcn_sched_barrier(0);
            LOADA(kt + 2 <= 31 ? kt + 2 : 31);   // newest (stays in flight)
            COMPUTE(cur);
            asm volatile("s_waitcnt vmcnt(2) lgkmcnt(0)" ::: "memory");
            __builtin_amdgcn_sched_barrier(0);
            __builtin_amdgcn_s_barrier();
        } else {
            COMPUTE(cur);
            asm volatile("s_waitcnt vmcnt(0) lgkmcnt(0)" ::: "memory");
            __builtin_amdgcn_sched_barrier(0);
        }
    }

    // ---- epilogue ----
    float* bnF = reinterpret_cast<float*>(lds);
    if (BN) {
        if (tid < 256) { bnF[tid] = 0.f; bnF[256 + tid] = 0.f; }
        __syncthreads();
    }
#pragma unroll
    for (int j = 0; j < NJ; ++j) {
        int cl  = wn0 + j * 16 + ln;
        int col = n0 + cl;
        float bj = (MODE == 0 && bias) ? bias[col] : 0.f;
        float sv = 0.f, sq = 0.f;
#pragma unroll
        for (int i = 0; i < 4; ++i) {
            int rbase = m0g + wm0 + i * 16 + (lane >> 4) * 4;
#pragma unroll
            for (int e = 0; e < 4; ++e) {
                size_t off = (size_t)(rbase + e) * Dd + col;
                float v = acc[i][j][e] + bj;
                if (MODE >= 1) v += Sin[off];
                Cout[off] = v;
                if (BN) { sv += v; sq += v * v; }
            }
        }
        if (BN) { atomicAdd(&bnF[cl], sv); atomicAdd(&bnF[256 + cl], sq); }
    }
    if (BN) {
        __syncthreads();
        if (tid < 256) {
            psum[(size_t)blockIdx.y * Dd + n0 + tid] = bnF[tid];
            psq [(size_t)blockIdx.y * Dd + n0 + tid] = bnF[256 + tid];
        }
    }
}

// ---------------------------------------------------------------------------
__global__ __launch_bounds__(256)
void bn_stats(const float* __restrict__ ps, const float* __restrict__ pq,
              const float* __restrict__ scale, const float* __restrict__ bias,
              float* __restrict__ Av, float* __restrict__ Cv)
{
    const int d = blockIdx.x * 256 + threadIdx.x;
    float s = 0.f, q = 0.f;
    for (int p = 0; p < 256; ++p) {
        s += ps[p * Dd + d];
        q += pq[p * Dd + d];
    }
    const float invN = 1.0f / 32768.0f;
    float mean = s * invN;
    float var  = q * invN - mean * mean;
    float rs   = rsqrtf(var + 1e-5f);
    float a    = rs * scale[d];
    Av[d] = a;
    Cv[d] = bias[d] - mean * a;
}

// ---------------------------------------------------------------------------
__global__ __launch_bounds__(256)
void residual_gelu(const float* __restrict__ Z, const float* __restrict__ Yin,
                   float* __restrict__ Yout,
                   const float* __restrict__ Av, const float* __restrict__ Cv)
{
    const float4* z4 = reinterpret_cast<const float4*>(Z);
    const float4* y4 = reinterpret_cast<const float4*>(Yin);
    float4*       o4 = reinterpret_cast<float4*>(Yout);
    const float4* a4 = reinterpret_cast<const float4*>(Av);
    const float4* c4 = reinterpret_cast<const float4*>(Cv);
    const int n4 = MTOT * Dd / 4;
    for (int i = blockIdx.x * blockDim.x + threadIdx.x; i < n4;
         i += gridDim.x * blockDim.x) {
        int d4 = i & (Dd / 4 - 1);
        float4 z = z4[i], y = y4[i], a = a4[d4], c = c4[d4];
        float4 o;
        o.x = gelu_tanh(fmaf(z.x, a.x, c.x)) + y.x;
        o.y = gelu_tanh(fmaf(z.y, a.y, c.y)) + y.y;
        o.z = gelu_tanh(fmaf(z.z, a.z, c.z)) + y.z;
        o.w = gelu_tanh(fmaf(z.w, a.w, c.w)) + y.w;
        o4[i] = o;
    }
}

// ---------------------------------------------------------------------------
extern "C" void kernel_launch(void* const* d_in, const int* in_sizes, int n_in,
                              void* d_out, int out_size, void* d_ws, size_t ws_size,
                              hipStream_t stream)
{
    const float* x    = (const float*)d_in[0];
    const float* Wi   = (const float*)d_in[1];
    const float* bi   = (const float*)d_in[2];
    const float* Wh   = (const float*)d_in[3];
    const float* mlpW = (const float*)d_in[4];
    const float* mlpb = (const float*)d_in[5];
    const float* bns  = (const float*)d_in[6];
    const float* bnb  = (const float*)d_in[7];
    float* out = (float*)d_out;

    float* ws   = (float*)d_ws;
    float* S0   = ws;                                  // 32M floats (128 MiB)
    float* Pa   = S0 + (size_t)MTOT * Dd;
    float* Pb   = Pa + (size_t)Dd * Dd;
    float* psum = Pb + (size_t)Dd * Dd;                // [256][1024]
    float* psq  = psum + 256 * Dd;
    float* abuf = psq + 256 * Dd;
    float* cbuf = abuf + Dd;
    short* Bth  = (short*)(cbuf + Dd);
    short* Btl  = Bth + (size_t)Dd * Dd;

    const dim3 gBig(4, 256);    // NT=256 tiles: 128x256, 512 threads
    const dim3 gSq (8, 8);      // NT=128 tiles: 128x128 (64 blocks)
    const dim3 gSeq(8, 16);     // NT=128 tiles (128 blocks)
    const dim3 gBt (32, 32);

#define SPLIT(M) split_bt<<<gBt, 256, 0, stream>>>((M), Bth, Btl)
#define GEMM(MODE, BN, NT, grid, A_, bias_, Sin_, C_, ps_, pq_, m_, ts_)      \
    mfma_gemm<MODE, BN, NT><<<grid, 512, 0, stream>>>(                        \
        (A_), Bth, Btl, (bias_), (Sin_), (C_), (ps_), (pq_), (m_), (ts_))

    // Phase 1: xp = x @ Wi + bi -> S0
    SPLIT(Wi);
    GEMM(0, 0, 256, gBig, x, bi, nullptr, S0, nullptr, nullptr, 0, 0);

    // Phase 2: 7 scan-doubling levels (window 128), powers interleaved.
    SPLIT(Wh);
    GEMM(1, 0, 256, gBig, S0, nullptr, S0, out, nullptr, nullptr, 1, 0);   // L1
    GEMM(0, 0, 128, gSq,  Wh, nullptr, nullptr, Pa, nullptr, nullptr, 0, 0); // P2
    SPLIT(Pa);
    GEMM(1, 0, 256, gBig, out, nullptr, out, S0, nullptr, nullptr, 2, 0);  // L2
    GEMM(0, 0, 128, gSq,  Pa, nullptr, nullptr, Pb, nullptr, nullptr, 0, 0); // P4
    SPLIT(Pb);
    GEMM(1, 0, 256, gBig, S0, nullptr, S0, out, nullptr, nullptr, 4, 0);   // L3
    GEMM(0, 0, 128, gSq,  Pb, nullptr, nullptr, Pa, nullptr, nullptr, 0, 0); // P8
    SPLIT(Pa);
    GEMM(1, 0, 256, gBig, out, nullptr, out, S0, nullptr, nullptr, 8, 0);  // L4
    GEMM(0, 0, 128, gSq,  Pa, nullptr, nullptr, Pb, nullptr, nullptr, 0, 0); // P16
    SPLIT(Pb);
    GEMM(1, 0, 256, gBig, S0, nullptr, S0, out, nullptr, nullptr, 16, 0);  // L5
    GEMM(0, 0, 128, gSq,  Pb, nullptr, nullptr, Pa, nullptr, nullptr, 0, 0); // P32
    SPLIT(Pa);
    GEMM(1, 0, 256, gBig, out, nullptr, out, S0, nullptr, nullptr, 32, 0); // L6
    GEMM(0, 0, 128, gSq,  Pa, nullptr, nullptr, Pb, nullptr, nullptr, 0, 0); // P64
    SPLIT(Pb);
    GEMM(1, 0, 256, gBig, S0, nullptr, S0, out, nullptr, nullptr, 64, 0);  // L7
    GEMM(0, 0, 128, gSq,  Pb, nullptr, nullptr, Pa, nullptr, nullptr, 0, 0); // P128
    SPLIT(Pa);

    // Phase 3: 15 sequential carry steps with P128 (in-place on out)
    for (int i = 1; i < 16; ++i)
        GEMM(2, 0, 128, gSeq, out, nullptr, out, out, nullptr, nullptr,
             128, 128 * i);

    // Phase 4: residual MLP stack; y stays in out, z in S0
    for (int l = 0; l < NL; ++l) {
        SPLIT(mlpW + (size_t)l * Dd * Dd);
        GEMM(0, 1, 256, gBig, out, mlpb + (size_t)l * Dd, nullptr, S0,
             psum, psq, 0, 0);
        bn_stats<<<4, 256, 0, stream>>>(psum, psq, bns + (size_t)l * Dd,
                                        bnb + (size_t)l * Dd, abuf, cbuf);
        residual_gelu<<<2048, 256, 0, stream>>>(S0, out, out, abuf, cbuf);
    }
#undef SPLIT
#undef GEMM
}

// Round 9
// 4510.690 us; speedup vs baseline: 1.0643x; 1.0447x over previous
//
#include <hip/hip_runtime.h>
#include <math.h>

#define Bb   16
#define Tt   2048
#define Dd   1024
#define NL   4
#define MTOT (Bb * Tt)   // 32768

typedef float f32x4 __attribute__((ext_vector_type(4)));
typedef short bf16x8 __attribute__((ext_vector_type(8)));

// ---------------------------------------------------------------------------
__device__ __forceinline__ unsigned short f2bf_rne(float x) {
    unsigned u = __float_as_uint(x);
    u += 0x7fffu + ((u >> 16) & 1u);
    return (unsigned short)(u >> 16);
}
__device__ __forceinline__ float bf2f(unsigned short h) {
    return __uint_as_float(((unsigned)h) << 16);
}
__device__ __forceinline__ float gelu_tanh(float x) {
    float x3 = x * x * x;
    float u  = 0.7978845608028654f * (x + 0.044715f * x3);
    return 0.5f * x * (1.0f + tanhf(u));
}
// async 16B global -> LDS (HW: wave-uniform LDS base + lane*16)
__device__ __forceinline__ void dma16(const void* g, void* l) {
    __builtin_amdgcn_global_load_lds(
        (const __attribute__((address_space(1))) unsigned int*)g,
        (__attribute__((address_space(3))) unsigned int*)l, 16, 0, 0);
}

// ---------------------------------------------------------------------------
// Split a [1024,1024] fp32 matrix (row-major [k][n]) into bf16 hi/lo with
// k-tiled, slot-swizzled layout:
//   fragment (n, kt, sl) -> shorts offset ((kt*1024+n)*4 + (sl^((n>>1)&3)))*8
// (unchanged — proven R6)
// ---------------------------------------------------------------------------
__global__ __launch_bounds__(256)
void split_bt(const float* __restrict__ B, short* __restrict__ ht,
              short* __restrict__ lt)
{
    __shared__ float tile[32][33];
    const int t  = threadIdx.x;
    const int r  = t >> 3;          // 0..31
    const int c  = (t & 7) * 4;     // 0,4,...,28
    const int kb = blockIdx.y * 32; // kt = blockIdx.y
    const int nb = blockIdx.x * 32;
    float4 v = *reinterpret_cast<const float4*>(
        &B[(size_t)(kb + r) * Dd + nb + c]);
    tile[r][c + 0] = v.x; tile[r][c + 1] = v.y;
    tile[r][c + 2] = v.z; tile[r][c + 3] = v.w;
    __syncthreads();
    unsigned h[4], lo[4];
#pragma unroll
    for (int q = 0; q < 4; ++q) {
        float f = tile[c + q][r];           // B[kb+c+q][nb+r]
        unsigned short hh = f2bf_rne(f);
        float rem = f - bf2f(hh);
        h[q]  = hh;
        lo[q] = f2bf_rne(rem);
    }
    uint2 hw, lw;
    hw.x = h[0]  | (h[1]  << 16); hw.y = h[2]  | (h[3]  << 16);
    lw.x = lo[0] | (lo[1] << 16); lw.y = lo[2] | (lo[3] << 16);
    const int n = nb + r;
    const int s = (c >> 3) ^ ((n >> 1) & 3);   // swizzled slot
    size_t off = ((size_t)(blockIdx.y * 1024 + n) * 4 + s) * 8 + (c & 4);
    *reinterpret_cast<uint2*>(&ht[off]) = hw;
    *reinterpret_cast<uint2*>(&lt[off]) = lw;
}

// ---------------------------------------------------------------------------
// BIG split-precision MFMA GEMM: tile 256x256, 1024 threads = 16 waves
// (4M x 4N, each wave 64x64). R6's proven 2-barrier-per-k-tile structure:
//   sync; stage A (load+convert+ds_write) + B (dma16); sync; compute.
// 4 waves/SIMD of intra-block TLP replaces R6's 2-block overlap.
// MODE 0: Cout = A@B (+bias)                        grid (4, 128)
// MODE 1: Cout[t] = Sin[t] + (t%Tt>=m ? A[t-m]@B : 0)
// BN 1:   also emit per-(m-tile, column) partial sum/sumsq (reuses LDS).
// LDS 72 KB: Ah[0,10240) Al[10240,20480) Bh[20480,28672) Bl[28672,36864)
// ---------------------------------------------------------------------------
template<int MODE, int BN>
__global__ __launch_bounds__(1024, 4)
void mfma_gemm_b(const float* __restrict__ A,
                 const short* __restrict__ Bth, const short* __restrict__ Btl,
                 const float* __restrict__ bias,
                 const float* __restrict__ Sin,
                 float* __restrict__ Cout,
                 float* __restrict__ psum, float* __restrict__ psq,
                 int m)
{
    constexpr int AP  = 10240;           // shorts per A plane (256 rows * 40)
    constexpr int BH  = 2 * AP;          // B hi base
    constexpr int BPL = 256 * 32;        // 8192 shorts per B plane
    __shared__ __align__(16) short lds[BH + 2 * BPL];   // 36864 shorts

    const int tid  = threadIdx.x;
    const int lane = tid & 63;
    const int w    = tid >> 6;           // 0..15
    const int n0   = blockIdx.x * 256;
    const int m0g  = blockIdx.y * 256;
    const int wm0  = (w >> 2) * 64;
    const int wn0  = (w & 3) * 64;

    // ---- A staging map: one row per thread, 8 k-elems ----
    const int ar = tid >> 2;             // 0..255
    const int ac = (tid & 3) * 8;        // 0,8,16,24
    const int rg = m0g + ar;
    bool avalid = true;
    if (MODE == 1) avalid = ((rg & (Tt - 1)) >= m);
    const size_t arow = (size_t)((MODE == 1 && avalid) ? (rg - m) : rg);
    const int awo = ar * 40 + ac;

    // ---- fragment read offsets ----
    int a_off[4];
#pragma unroll
    for (int i = 0; i < 4; ++i)
        a_off[i] = (wm0 + i * 16 + (lane & 15)) * 40 + (lane >> 4) * 8;
    const int ln  = lane & 15;
    const int nlb = wn0 + ln;
    const int b_off0 = BH + nlb * 32 + (((lane >> 4) ^ ((nlb >> 1) & 3)) << 3);

    // ---- B dma map: fragment index = tid ----
    const size_t bfrag = (size_t)(n0 + (tid >> 2)) * 4 + (tid & 3);

    f32x4 acc[4][4];
#pragma unroll
    for (int i = 0; i < 4; ++i)
#pragma unroll
        for (int j = 0; j < 4; ++j) acc[i][j] = (f32x4){0.f, 0.f, 0.f, 0.f};

    for (int kt = 0; kt < 32; ++kt) {
        __syncthreads();   // previous tile's ds_reads complete
        // ---- stage A: global fp32 -> (hi, lo) bf16 -> LDS ----
        {
            const float* p = &A[arow * Dd + kt * 32 + ac];
            float4 v0 = *reinterpret_cast<const float4*>(p);
            float4 v1 = *reinterpret_cast<const float4*>(p + 4);
            float f[8] = {v0.x, v0.y, v0.z, v0.w, v1.x, v1.y, v1.z, v1.w};
            if (MODE == 1 && !avalid) {
#pragma unroll
                for (int e = 0; e < 8; ++e) f[e] = 0.f;
            }
            unsigned hh[8], ll[8];
#pragma unroll
            for (int e = 0; e < 8; ++e) {
                unsigned short h = f2bf_rne(f[e]);
                hh[e] = h;
                ll[e] = f2bf_rne(f[e] - bf2f(h));
            }
            int4 hw, lw;
            hw.x = (int)(hh[0] | (hh[1] << 16)); hw.y = (int)(hh[2] | (hh[3] << 16));
            hw.z = (int)(hh[4] | (hh[5] << 16)); hw.w = (int)(hh[6] | (hh[7] << 16));
            lw.x = (int)(ll[0] | (ll[1] << 16)); lw.y = (int)(ll[2] | (ll[3] << 16));
            lw.z = (int)(ll[4] | (ll[5] << 16)); lw.w = (int)(ll[6] | (ll[7] << 16));
            *reinterpret_cast<int4*>(&lds[awo])      = hw;
            *reinterpret_cast<int4*>(&lds[awo + AP]) = lw;
        }
        // ---- stage B: async DMA (linear LDS dest, pre-swizzled source) ----
        {
            size_t g = ((size_t)kt * 1024 * 4 + bfrag) * 8;
            dma16(&Bth[g], &lds[BH + w * 512]);
            dma16(&Btl[g], &lds[BH + BPL + w * 512]);
        }
        __syncthreads();   // drains vmcnt (DMA) + lgkm (A writes)
        // ---- compute ----
        bf16x8 ah[4], al[4];
#pragma unroll
        for (int i = 0; i < 4; ++i) {
            ah[i] = *reinterpret_cast<const bf16x8*>(&lds[a_off[i]]);
            al[i] = *reinterpret_cast<const bf16x8*>(&lds[a_off[i] + AP]);
        }
#pragma unroll
        for (int j = 0; j < 4; ++j) {
            const bf16x8 bh = *reinterpret_cast<const bf16x8*>(
                &lds[b_off0 + j * 512]);
            const bf16x8 bl = *reinterpret_cast<const bf16x8*>(
                &lds[b_off0 + j * 512 + BPL]);
#pragma unroll
            for (int i = 0; i < 4; ++i) {
                acc[i][j] = __builtin_amdgcn_mfma_f32_16x16x32_bf16(
                    ah[i], bh, acc[i][j], 0, 0, 0);
                acc[i][j] = __builtin_amdgcn_mfma_f32_16x16x32_bf16(
                    ah[i], bl, acc[i][j], 0, 0, 0);
                acc[i][j] = __builtin_amdgcn_mfma_f32_16x16x32_bf16(
                    al[i], bh, acc[i][j], 0, 0, 0);
            }
        }
    }

    // ---- epilogue ----
    float* bnF = reinterpret_cast<float*>(lds);
    if (BN) {
        __syncthreads();               // all LDS reads done; reuse as floats
        if (tid < 256) { bnF[tid] = 0.f; bnF[256 + tid] = 0.f; }
        __syncthreads();
    }
#pragma unroll
    for (int j = 0; j < 4; ++j) {
        int cl  = wn0 + j * 16 + ln;
        int col = n0 + cl;
        float bj = (MODE == 0 && bias) ? bias[col] : 0.f;
        float sv = 0.f, sq = 0.f;
#pragma unroll
        for (int i = 0; i < 4; ++i) {
            int rbase = m0g + wm0 + i * 16 + (lane >> 4) * 4;
#pragma unroll
            for (int e = 0; e < 4; ++e) {
                size_t off = (size_t)(rbase + e) * Dd + col;
                float v = acc[i][j][e] + bj;
                if (MODE == 1) v += Sin[off];
                Cout[off] = v;
                if (BN) { sv += v; sq += v * v; }
            }
        }
        if (BN) { atomicAdd(&bnF[cl], sv); atomicAdd(&bnF[256 + cl], sq); }
    }
    if (BN) {
        __syncthreads();
        if (tid < 256) {
            psum[(size_t)blockIdx.y * Dd + n0 + tid] = bnF[tid];
            psq [(size_t)blockIdx.y * Dd + n0 + tid] = bnF[256 + tid];
        }
    }
}

// ---------------------------------------------------------------------------
// SMALL kernel: R6's proven 256-thread 128x128 structure (2 blocks/CU) for
// the 1024^3 power squarings (MODE 0) and seq carries (MODE 2).
// ---------------------------------------------------------------------------
template<int MODE>
__global__ __launch_bounds__(256, 2)
void mfma_gemm_s(const float* __restrict__ A,
                 const short* __restrict__ Bth, const short* __restrict__ Btl,
                 const float* __restrict__ Sin,
                 float* __restrict__ Cout,
                 int m, int tstart)
{
    constexpr int NT  = 128;
    constexpr int NJ  = NT / 32;         // 4
    constexpr int BH  = 10240;
    constexpr int BPL = NT * 32;         // 4096
    __shared__ __align__(16) short lds[BH + 2 * BPL];

    const int tid  = threadIdx.x;
    const int lane = tid & 63;
    const int w    = tid >> 6;
    const int n0   = blockIdx.x * NT;
    const int m0g  = (MODE == 2) ? (blockIdx.y * Tt + tstart)
                                 : (blockIdx.y * 128);
    const int wm0  = (w >> 1) * 64;
    const int wn0  = (w & 1) * 64;
    const int ar   = tid >> 3;
    const int ac   = (tid & 7) * 4;

    int  arow_src[4];
#pragma unroll
    for (int p = 0; p < 4; ++p) {
        int rgp = m0g + p * 32 + ar;
        arow_src[p] = (MODE == 2) ? (rgp - m) : rgp;
    }

    f32x4 acc[4][NJ];
#pragma unroll
    for (int i = 0; i < 4; ++i)
#pragma unroll
        for (int j = 0; j < NJ; ++j) acc[i][j] = (f32x4){0.f, 0.f, 0.f, 0.f};

    int a_off[4];
#pragma unroll
    for (int i = 0; i < 4; ++i)
        a_off[i] = (wm0 + i * 16 + (lane & 15)) * 40 + (lane >> 4) * 8;
    const int ln  = lane & 15;
    const int nlb = wn0 + ln;
    const int b_off0 = BH + nlb * 32 + (((lane >> 4) ^ ((nlb >> 1) & 3)) << 3);

    for (int k0 = 0; k0 < Dd; k0 += 32) {
        __syncthreads();
#pragma unroll
        for (int p = 0; p < 4; ++p) {
            float4 v = *reinterpret_cast<const float4*>(
                &A[(size_t)arow_src[p] * Dd + k0 + ac]);
            int wo = (p * 32 + ar) * 40 + ac;
            unsigned short h0 = f2bf_rne(v.x), h1 = f2bf_rne(v.y),
                           h2 = f2bf_rne(v.z), h3 = f2bf_rne(v.w);
            unsigned short g0 = f2bf_rne(v.x - bf2f(h0)),
                           g1 = f2bf_rne(v.y - bf2f(h1)),
                           g2 = f2bf_rne(v.z - bf2f(h2)),
                           g3 = f2bf_rne(v.w - bf2f(h3));
            uint2 hw, lw;
            hw.x = (unsigned)h0 | ((unsigned)h1 << 16);
            hw.y = (unsigned)h2 | ((unsigned)h3 << 16);
            lw.x = (unsigned)g0 | ((unsigned)g1 << 16);
            lw.y = (unsigned)g2 | ((unsigned)g3 << 16);
            *reinterpret_cast<uint2*>(&lds[wo])        = hw;
            *reinterpret_cast<uint2*>(&lds[wo + 5120]) = lw;
        }
        {
            const int kt = k0 >> 5;
#pragma unroll
            for (int q = 0; q < NT / 64; ++q) {
                size_t gfo = ((size_t)(kt * 1024 + n0 + q * 64 + (tid >> 2))
                              * 4 + (tid & 3)) * 8;
                dma16(&Bth[gfo], &lds[BH + q * 2048 + w * 512]);
                dma16(&Btl[gfo], &lds[BH + BPL + q * 2048 + w * 512]);
            }
        }
        __syncthreads();
        bf16x8 ah[4], al[4];
#pragma unroll
        for (int i = 0; i < 4; ++i) {
            ah[i] = *reinterpret_cast<const bf16x8*>(&lds[a_off[i]]);
            al[i] = *reinterpret_cast<const bf16x8*>(&lds[a_off[i] + 5120]);
        }
#pragma unroll
        for (int j = 0; j < NJ; ++j) {
            const bf16x8 bh = *reinterpret_cast<const bf16x8*>(
                &lds[b_off0 + j * 512]);
            const bf16x8 bl = *reinterpret_cast<const bf16x8*>(
                &lds[b_off0 + j * 512 + BPL]);
#pragma unroll
            for (int i = 0; i < 4; ++i) {
                acc[i][j] = __builtin_amdgcn_mfma_f32_16x16x32_bf16(
                    ah[i], bh, acc[i][j], 0, 0, 0);
                acc[i][j] = __builtin_amdgcn_mfma_f32_16x16x32_bf16(
                    ah[i], bl, acc[i][j], 0, 0, 0);
                acc[i][j] = __builtin_amdgcn_mfma_f32_16x16x32_bf16(
                    al[i], bh, acc[i][j], 0, 0, 0);
            }
        }
    }

#pragma unroll
    for (int j = 0; j < NJ; ++j) {
        int col = n0 + wn0 + j * 16 + ln;
#pragma unroll
        for (int i = 0; i < 4; ++i) {
            int rbase = m0g + wm0 + i * 16 + (lane >> 4) * 4;
#pragma unroll
            for (int e = 0; e < 4; ++e) {
                size_t off = (size_t)(rbase + e) * Dd + col;
                float v = acc[i][j][e];
                if (MODE == 2) v += Sin[off];
                Cout[off] = v;
            }
        }
    }
}

// ---------------------------------------------------------------------------
__global__ __launch_bounds__(256)
void bn_stats(const float* __restrict__ ps, const float* __restrict__ pq,
              const float* __restrict__ scale, const float* __restrict__ bias,
              float* __restrict__ Av, float* __restrict__ Cv)
{
    const int d = blockIdx.x * 256 + threadIdx.x;
    float s = 0.f, q = 0.f;
    for (int p = 0; p < 128; ++p) {
        s += ps[p * Dd + d];
        q += pq[p * Dd + d];
    }
    const float invN = 1.0f / 32768.0f;
    float mean = s * invN;
    float var  = q * invN - mean * mean;
    float rs   = rsqrtf(var + 1e-5f);
    float a    = rs * scale[d];
    Av[d] = a;
    Cv[d] = bias[d] - mean * a;
}

// ---------------------------------------------------------------------------
__global__ __launch_bounds__(256)
void residual_gelu(const float* __restrict__ Z, const float* __restrict__ Yin,
                   float* __restrict__ Yout,
                   const float* __restrict__ Av, const float* __restrict__ Cv)
{
    const float4* z4 = reinterpret_cast<const float4*>(Z);
    const float4* y4 = reinterpret_cast<const float4*>(Yin);
    float4*       o4 = reinterpret_cast<float4*>(Yout);
    const float4* a4 = reinterpret_cast<const float4*>(Av);
    const float4* c4 = reinterpret_cast<const float4*>(Cv);
    const int n4 = MTOT * Dd / 4;
    for (int i = blockIdx.x * blockDim.x + threadIdx.x; i < n4;
         i += gridDim.x * blockDim.x) {
        int d4 = i & (Dd / 4 - 1);
        float4 z = z4[i], y = y4[i], a = a4[d4], c = c4[d4];
        float4 o;
        o.x = gelu_tanh(fmaf(z.x, a.x, c.x)) + y.x;
        o.y = gelu_tanh(fmaf(z.y, a.y, c.y)) + y.y;
        o.z = gelu_tanh(fmaf(z.z, a.z, c.z)) + y.z;
        o.w = gelu_tanh(fmaf(z.w, a.w, c.w)) + y.w;
        o4[i] = o;
    }
}

// ---------------------------------------------------------------------------
extern "C" void kernel_launch(void* const* d_in, const int* in_sizes, int n_in,
                              void* d_out, int out_size, void* d_ws, size_t ws_size,
                              hipStream_t stream)
{
    const float* x    = (const float*)d_in[0];
    const float* Wi   = (const float*)d_in[1];
    const float* bi   = (const float*)d_in[2];
    const float* Wh   = (const float*)d_in[3];
    const float* mlpW = (const float*)d_in[4];
    const float* mlpb = (const float*)d_in[5];
    const float* bns  = (const float*)d_in[6];
    const float* bnb  = (const float*)d_in[7];
    float* out = (float*)d_out;

    float* ws   = (float*)d_ws;
    float* S0   = ws;                                  // 32M floats (128 MiB)
    float* Pa   = S0 + (size_t)MTOT * Dd;
    float* Pb   = Pa + (size_t)Dd * Dd;
    float* psum = Pb + (size_t)Dd * Dd;                // [128][1024]
    float* psq  = psum + 256 * Dd;
    float* abuf = psq + 256 * Dd;
    float* cbuf = abuf + Dd;
    short* Bth  = (short*)(cbuf + Dd);
    short* Btl  = Bth + (size_t)Dd * Dd;

    const dim3 gBig(4, 128);    // 256x256 tiles, 1024 threads
    const dim3 gSq (8, 8);      // 128x128 tiles, 256 threads
    const dim3 gSeq(8, 16);
    const dim3 gBt (32, 32);

#define SPLIT(M) split_bt<<<gBt, 256, 0, stream>>>((M), Bth, Btl)
#define GEMMB(MODE, BN, A_, bias_, Sin_, C_, ps_, pq_, m_)                    \
    mfma_gemm_b<MODE, BN><<<gBig, 1024, 0, stream>>>(                         \
        (A_), Bth, Btl, (bias_), (Sin_), (C_), (ps_), (pq_), (m_))
#define GEMMS(MODE, grid, A_, Sin_, C_, m_, ts_)                              \
    mfma_gemm_s<MODE><<<grid, 256, 0, stream>>>(                              \
        (A_), Bth, Btl, (Sin_), (C_), (m_), (ts_))

    // Phase 1: xp = x @ Wi + bi -> S0
    SPLIT(Wi);
    GEMMB(0, 0, x, bi, nullptr, S0, nullptr, nullptr, 0);

    // Phase 2: 7 scan-doubling levels (window 128), powers interleaved.
    SPLIT(Wh);
    GEMMB(1, 0, S0, nullptr, S0, out, nullptr, nullptr, 1);   // L1
    GEMMS(0, gSq, Wh, nullptr, Pa, 0, 0);                      // P2
    SPLIT(Pa);
    GEMMB(1, 0, out, nullptr, out, S0, nullptr, nullptr, 2);  // L2
    GEMMS(0, gSq, Pa, nullptr, Pb, 0, 0);                      // P4
    SPLIT(Pb);
    GEMMB(1, 0, S0, nullptr, S0, out, nullptr, nullptr, 4);   // L3
    GEMMS(0, gSq, Pb, nullptr, Pa, 0, 0);                      // P8
    SPLIT(Pa);
    GEMMB(1, 0, out, nullptr, out, S0, nullptr, nullptr, 8);  // L4
    GEMMS(0, gSq, Pa, nullptr, Pb, 0, 0);                      // P16
    SPLIT(Pb);
    GEMMB(1, 0, S0, nullptr, S0, out, nullptr, nullptr, 16);  // L5
    GEMMS(0, gSq, Pb, nullptr, Pa, 0, 0);                      // P32
    SPLIT(Pa);
    GEMMB(1, 0, out, nullptr, out, S0, nullptr, nullptr, 32); // L6
    GEMMS(0, gSq, Pa, nullptr, Pb, 0, 0);                      // P64
    SPLIT(Pb);
    GEMMB(1, 0, S0, nullptr, S0, out, nullptr, nullptr, 64);  // L7 -> out
    GEMMS(0, gSq, Pb, nullptr, Pa, 0, 0);                      // P128
    SPLIT(Pa);

    // Phase 3: 15 sequential carry steps with P128 (in-place on out)
    for (int i = 1; i < 16; ++i)
        GEMMS(2, gSeq, out, out, out, 128, 128 * i);

    // Phase 4: residual MLP stack; y stays in out, z in S0
    for (int l = 0; l < NL; ++l) {
        SPLIT(mlpW + (size_t)l * Dd * Dd);
        GEMMB(0, 1, out, mlpb + (size_t)l * Dd, nullptr, S0, psum, psq, 0);
        bn_stats<<<4, 256, 0, stream>>>(psum, psq, bns + (size_t)l * Dd,
                                        bnb + (size_t)l * Dd, abuf, cbuf);
        residual_gelu<<<2048, 256, 0, stream>>>(S0, out, out, abuf, cbuf);
    }
#undef SPLIT
#undef GEMMB
#undef GEMMS
}